// Round 4
// baseline (71.478 us; speedup 1.0000x reference)
//
#include <hip/hip_runtime.h>
#include <math.h>

#define HDIM 2048
#define NEXP 8
#define TB 2                         // tokens per wave
#define BLOCK 256
#define WAVES_PB (BLOCK / 64)        // 4
#define TOK_PB (WAVES_PB * TB)       // 8 tokens per block

// ---------------------------------------------------------------------------
// One wave handles TB=2 tokens; 2048 blocks x 4 waves = 8192 waves so the
// chip can hold 32 waves/CU (requires VGPR <= 64 -> launch_bounds(256,8)).
// Lanes split H (float4 each); W processed in two 4-expert halves per iter
// to cap live W registers at 16. Shuffle fold leaves lane l holding
// logit(token (l>>3)&1, expert l&7). Top-2 + softmax in-register;
// histogram via LDS counts + 8 float atomics per block (integer-valued
// float adds < 2^24 are exact -> deterministic).
// ---------------------------------------------------------------------------
__global__ __launch_bounds__(BLOCK, 8) void
router_main(const float* __restrict__ x,
            const float* __restrict__ W,
            float* __restrict__ out_scores,   // [T,2]
            float* __restrict__ out_idx,      // [T,2] as float
            float* __restrict__ hist,         // [8], pre-zeroed
            int T)
{
    __shared__ int cnt[NEXP];
    if (threadIdx.x < NEXP) cnt[threadIdx.x] = 0;
    __syncthreads();

    const int lane = threadIdx.x & 63;
    const int wv   = threadIdx.x >> 6;
    const int tok0 = blockIdx.x * TOK_PB + wv * TB;

    int t0 = tok0 + 0; if (t0 > T - 1) t0 = T - 1;
    int t1 = tok0 + 1; if (t1 > T - 1) t1 = T - 1;
    const float* xb0 = x + (size_t)t0 * HDIM + lane * 4;
    const float* xb1 = x + (size_t)t1 * HDIM + lane * 4;
    const float* wb  = W + lane * 4;

    float acc[16];
#pragma unroll
    for (int i = 0; i < 16; ++i) acc[i] = 0.f;

    // unroll 2 (not 8): keeps hoisting bounded so we stay under 64 VGPRs
#pragma unroll 2
    for (int iter = 0; iter < HDIM / 256; ++iter) {
        const int h = iter * 256;
        const float4 x0 = *reinterpret_cast<const float4*>(xb0 + h);
        const float4 x1 = *reinterpret_cast<const float4*>(xb1 + h);
#pragma unroll
        for (int half = 0; half < 2; ++half) {
            const int b = half * 4;
            const float4 w0 = *reinterpret_cast<const float4*>(wb + (size_t)(b + 0) * HDIM + h);
            const float4 w1 = *reinterpret_cast<const float4*>(wb + (size_t)(b + 1) * HDIM + h);
            const float4 w2 = *reinterpret_cast<const float4*>(wb + (size_t)(b + 2) * HDIM + h);
            const float4 w3 = *reinterpret_cast<const float4*>(wb + (size_t)(b + 3) * HDIM + h);
            acc[b+0]  = fmaf(x0.w, w0.w, fmaf(x0.z, w0.z, fmaf(x0.y, w0.y, fmaf(x0.x, w0.x, acc[b+0]))));
            acc[b+1]  = fmaf(x0.w, w1.w, fmaf(x0.z, w1.z, fmaf(x0.y, w1.y, fmaf(x0.x, w1.x, acc[b+1]))));
            acc[b+2]  = fmaf(x0.w, w2.w, fmaf(x0.z, w2.z, fmaf(x0.y, w2.y, fmaf(x0.x, w2.x, acc[b+2]))));
            acc[b+3]  = fmaf(x0.w, w3.w, fmaf(x0.z, w3.z, fmaf(x0.y, w3.y, fmaf(x0.x, w3.x, acc[b+3]))));
            acc[b+8]  = fmaf(x1.w, w0.w, fmaf(x1.z, w0.z, fmaf(x1.y, w0.y, fmaf(x1.x, w0.x, acc[b+8]))));
            acc[b+9]  = fmaf(x1.w, w1.w, fmaf(x1.z, w1.z, fmaf(x1.y, w1.y, fmaf(x1.x, w1.x, acc[b+9]))));
            acc[b+10] = fmaf(x1.w, w2.w, fmaf(x1.z, w2.z, fmaf(x1.y, w2.y, fmaf(x1.x, w2.x, acc[b+10]))));
            acc[b+11] = fmaf(x1.w, w3.w, fmaf(x1.z, w3.z, fmaf(x1.y, w3.y, fmaf(x1.x, w3.x, acc[b+11]))));
        }
    }

    // ---- reduce 16 partial sums across 64 lanes (all static indices) ----
#pragma unroll
    for (int j = 0; j < 16; ++j) acc[j] += __shfl_xor(acc[j], 32, 64);
#pragma unroll
    for (int j = 0; j < 16; ++j) acc[j] += __shfl_xor(acc[j], 16, 64);

#define FOLD(SM)                                                          \
    {                                                                     \
        const bool up = (lane & SM) != 0;                                 \
        _Pragma("unroll")                                                 \
        for (int j = 0; j < SM; ++j) {                                    \
            float keep = up ? acc[j + SM] : acc[j];                       \
            float send = up ? acc[j] : acc[j + SM];                       \
            acc[j] = keep + __shfl_xor(send, SM, 64);                     \
        }                                                                 \
    }
    FOLD(8) FOLD(4) FOLD(2) FOLD(1)
#undef FOLD

    // lane l holds logit(token tok0 + ((l>>3)&1), expert l&7)
    const int e_my  = lane & 7;
    const int t_loc = (lane >> 3) & 1;
    const float mylg = acc[0];

    // ---- top-1 within each aligned 8-lane group (tie -> lower index) ----
    float v1 = mylg;
    int   i1 = e_my;
#pragma unroll
    for (int m = 1; m <= 4; m <<= 1) {
        float ov = __shfl_xor(v1, m, 64);
        int   oi = __shfl_xor(i1, m, 64);
        if (ov > v1 || (ov == v1 && oi < i1)) { v1 = ov; i1 = oi; }
    }
    // ---- top-2: exclude i1, repeat ----
    float v2 = (e_my == i1) ? -3.402823466e+38f : mylg;
    int   i2 = e_my;
#pragma unroll
    for (int m = 1; m <= 4; m <<= 1) {
        float ov = __shfl_xor(v2, m, 64);
        int   oi = __shfl_xor(i2, m, 64);
        if (ov > v2 || (ov == v2 && oi < i2)) { v2 = ov; i2 = oi; }
    }

    // ---- softmax over the 2 selected logits (fp32, stable: v1 >= v2) ----
    const float ed  = expf(v2 - v1);
    const float inv = 1.0f / (1.0f + ed);

    const int tok = tok0 + t_loc;
    if (lane < 16 && e_my == 0 && tok < T) {
        *reinterpret_cast<float2*>(out_scores + 2 * tok) = make_float2(inv, ed * inv);
        *reinterpret_cast<float2*>(out_idx    + 2 * tok) = make_float2((float)i1, (float)i2);
        atomicAdd(&cnt[i1], 1);
        atomicAdd(&cnt[i2], 1);
    }

    __syncthreads();
    if (threadIdx.x < NEXP)
        atomicAdd(&hist[threadIdx.x], (float)cnt[threadIdx.x]);
}

extern "C" void kernel_launch(void* const* d_in, const int* in_sizes, int n_in,
                              void* d_out, int out_size, void* d_ws, size_t ws_size,
                              hipStream_t stream)
{
    const float* x = (const float*)d_in[0];
    const float* W = (const float*)d_in[1];
    const int T = in_sizes[0] / HDIM;          // 16384

    float* out        = (float*)d_out;
    float* out_scores = out;                   // [T,2]
    float* out_idx    = out + (size_t)2 * T;   // [T,2]
    float* hist       = out + (size_t)4 * T;   // [8]

    // zero the 8 hist slots every call (atomics accumulate into them)
    hipMemsetAsync(hist, 0, NEXP * sizeof(float), stream);

    const int nblocks = (T + TOK_PB - 1) / TOK_PB;   // 2048
    router_main<<<nblocks, BLOCK, 0, stream>>>(x, W, out_scores, out_idx, hist, T);
}

// Round 5
// 39.956 us; speedup vs baseline: 1.7889x; 1.7889x over previous
//
#include <hip/hip_runtime.h>
#include <math.h>

#define HDIM 2048
#define NEXP 8
#define TB 4                          // tokens per wave
#define BLOCK 256
#define WAVES_PB 4
#define TOK_PB (WAVES_PB * TB)        // 16 tokens per block
#define CH 256                        // floats of H per chunk (1 KB/token)
#define NCH (HDIM / CH)               // 8 chunks

// ---------------------------------------------------------------------------
// Latency-proof router: x streamed via async global_load_lds (16B/lane, 1KB
// per instr) into per-wave LDS double-buffers -> in-flight bytes are not
// limited by VGPRs. Per-wave counted s_waitcnt vmcnt(8) pipeline, NO
// __syncthreads in the main loop. W chunk (8 x float4 = 32 regs) from L2
// each iteration. acc[32] = 4 tokens x 8 experts per lane; shuffle-fold
// epilogue (verified in R1) -> top-2 -> softmax -> stores + LDS histogram.
// ---------------------------------------------------------------------------
__global__ __launch_bounds__(BLOCK, 4) void
router_main(const float* __restrict__ x,
            const float* __restrict__ W,
            float* __restrict__ out_scores,   // [T,2]
            float* __restrict__ out_idx,      // [T,2] as float
            float* __restrict__ hist,         // [8], pre-zeroed
            int T)
{
    // [buf][wave][token][lane] float4 : 2*4*4*64*16 B = 32 KB
    __shared__ float4 xs[2][WAVES_PB][TB][64];
    __shared__ int cnt[NEXP];
    if (threadIdx.x < NEXP) cnt[threadIdx.x] = 0;
    __syncthreads();

    const int lane = threadIdx.x & 63;
    const int wv   = threadIdx.x >> 6;
    const int tok0 = blockIdx.x * TOK_PB + wv * TB;

    // per-token global source base (this lane's 16B slice)
    const float* xsrc[TB];
#pragma unroll
    for (int t = 0; t < TB; ++t) {
        int tt = tok0 + t; if (tt > T - 1) tt = T - 1;
        xsrc[t] = x + (size_t)tt * HDIM + lane * 4;
    }
    const float* wb = W + lane * 4;

    float acc[TB * NEXP];
#pragma unroll
    for (int i = 0; i < TB * NEXP; ++i) acc[i] = 0.f;

    // ---- prolog: chunk 0 -> buf 0 (async DMA, no VGPR destinations) ----
#pragma unroll
    for (int t = 0; t < TB; ++t)
        __builtin_amdgcn_global_load_lds(
            (const __attribute__((address_space(1))) void*)(xsrc[t]),
            (__attribute__((address_space(3))) void*)&xs[0][wv][t][0],
            16, 0, 0);

    // ---- main loop: no barriers, per-wave counted vmcnt pipeline ----
#pragma unroll 1
    for (int c = 0; c < NCH; ++c) {
        const int h = c * CH;

        // (1) W chunk loads -> registers (oldest after x_c in the vm queue)
        float4 w[NEXP];
#pragma unroll
        for (int e = 0; e < NEXP; ++e)
            w[e] = *reinterpret_cast<const float4*>(wb + (size_t)e * HDIM + h);

        // fence: keep W loads older than the prefetch DMA below
        asm volatile("" ::: "memory");

        // (2) prefetch chunk c+1 -> other buffer (stays in flight past the wait)
        if (c + 1 < NCH) {
#pragma unroll
            for (int t = 0; t < TB; ++t)
                __builtin_amdgcn_global_load_lds(
                    (const __attribute__((address_space(1))) void*)(xsrc[t] + h + CH),
                    (__attribute__((address_space(3))) void*)&xs[(c + 1) & 1][wv][t][0],
                    16, 0, 0);
        }

        // (3) counted wait: retire x_c (oldest 4) + half of W; leave the 4
        //     newest (x_{c+1} DMA) in flight. Compiler adds its own tighter
        //     wait before the first FMA use of w[].
        asm volatile("s_waitcnt vmcnt(8)" ::: "memory");

        // (4) compute chunk c from LDS
#pragma unroll
        for (int t = 0; t < TB; ++t) {
            const float4 xv = xs[c & 1][wv][t][lane];
#pragma unroll
            for (int e = 0; e < NEXP; ++e) {
                float a = acc[t * NEXP + e];
                a = fmaf(xv.x, w[e].x, a);
                a = fmaf(xv.y, w[e].y, a);
                a = fmaf(xv.z, w[e].z, a);
                a = fmaf(xv.w, w[e].w, a);
                acc[t * NEXP + e] = a;
            }
        }
    }

    // ---- reduce 32 partial sums across 64 lanes (R1-verified fold) ----
#pragma unroll
    for (int j = 0; j < 32; ++j) acc[j] += __shfl_xor(acc[j], 32, 64);

#define FOLD(SM)                                                          \
    {                                                                     \
        const bool up = (lane & SM) != 0;                                 \
        _Pragma("unroll")                                                 \
        for (int j = 0; j < SM; ++j) {                                    \
            float keep = up ? acc[j + SM] : acc[j];                       \
            float send = up ? acc[j] : acc[j + SM];                       \
            acc[j] = keep + __shfl_xor(send, SM, 64);                     \
        }                                                                 \
    }
    FOLD(16) FOLD(8) FOLD(4) FOLD(2) FOLD(1)
#undef FOLD

    // lane l holds logit(token tok0 + ((l&31)>>3), expert l&7)
    const int e_my  = lane & 7;
    const int t_loc = (lane & 31) >> 3;
    const float mylg = acc[0];

    // ---- top-1 within each aligned 8-lane group (tie -> lower index) ----
    float v1 = mylg;
    int   i1 = e_my;
#pragma unroll
    for (int m = 1; m <= 4; m <<= 1) {
        float ov = __shfl_xor(v1, m, 64);
        int   oi = __shfl_xor(i1, m, 64);
        if (ov > v1 || (ov == v1 && oi < i1)) { v1 = ov; i1 = oi; }
    }
    // ---- top-2: exclude i1, repeat ----
    float v2 = (e_my == i1) ? -3.402823466e+38f : mylg;
    int   i2 = e_my;
#pragma unroll
    for (int m = 1; m <= 4; m <<= 1) {
        float ov = __shfl_xor(v2, m, 64);
        int   oi = __shfl_xor(i2, m, 64);
        if (ov > v2 || (ov == v2 && oi < i2)) { v2 = ov; i2 = oi; }
    }

    // ---- softmax over the 2 selected logits (fp32, stable: v1 >= v2) ----
    const float ed  = expf(v2 - v1);
    const float inv = 1.0f / (1.0f + ed);

    const int tok = tok0 + t_loc;
    if (lane < 32 && e_my == 0 && tok < T) {
        *reinterpret_cast<float2*>(out_scores + 2 * tok) = make_float2(inv, ed * inv);
        *reinterpret_cast<float2*>(out_idx    + 2 * tok) = make_float2((float)i1, (float)i2);
        atomicAdd(&cnt[i1], 1);
        atomicAdd(&cnt[i2], 1);
    }

    __syncthreads();
    // integer-valued float adds (< 2^24) are exact -> order-independent,
    // deterministic across replays.
    if (threadIdx.x < NEXP)
        atomicAdd(&hist[threadIdx.x], (float)cnt[threadIdx.x]);
}

extern "C" void kernel_launch(void* const* d_in, const int* in_sizes, int n_in,
                              void* d_out, int out_size, void* d_ws, size_t ws_size,
                              hipStream_t stream)
{
    const float* x = (const float*)d_in[0];
    const float* W = (const float*)d_in[1];
    const int T = in_sizes[0] / HDIM;          // 16384

    float* out        = (float*)d_out;
    float* out_scores = out;                   // [T,2]
    float* out_idx    = out + (size_t)2 * T;   // [T,2]
    float* hist       = out + (size_t)4 * T;   // [8]

    // zero the 8 hist slots every call (atomics accumulate into them)
    hipMemsetAsync(hist, 0, NEXP * sizeof(float), stream);

    const int nblocks = (T + TOK_PB - 1) / TOK_PB;   // 1024
    router_main<<<nblocks, BLOCK, 0, stream>>>(x, W, out_scores, out_idx, hist, T);
}